// Round 3
// baseline (113.361 us; speedup 1.0000x reference)
//
#include <hip/hip_runtime.h>
#include <math.h>

// MovingZScoreNorm: x[32,8192,128] f32, W=24.
// mean: TF SAME avg-pool with valid-count; var: windowed sum of channel-summed
// sq / (W-1); out = (x-mean)/(sqrt(var)+eps).
//
// One wave per (batch, 64-row tile); lane owns 2 channels (float2).
// Single global load per iteration: x(s+24). Delayed rows live in a 36-row
// register delay line (3 rotating banks x 12, static indexing via unrolled
// chunks). Output mean = lead window-sum delayed 12 iters (register bank).
// sq_tot 24-delay in 3 rotating register banks. No LDS storage.
// TT=64 -> 4096 waves (16 waves/CU) for latency hiding.

constexpr int Sdim = 8192;
constexpr int Cdim = 128;
constexpr int TT   = 64;             // output rows per wave
constexpr int NTb  = Sdim / TT;      // 128 tiles per batch
constexpr float EPSv = 1e-7f;

__device__ __forceinline__ float wsum(float v) {
#pragma unroll
    for (int m = 1; m < 64; m <<= 1) v += __shfl_xor(v, m, 64);
    return v;
}

template<bool EDGE>
__device__ __forceinline__ float2 ldg(const float* __restrict__ base, int r) {
    if (EDGE && (unsigned)r >= (unsigned)Sdim) return make_float2(0.f, 0.f);
    return *reinterpret_cast<const float2*>(base + (size_t)r * Cdim);
}

// One chunk of NJ iterations s = cb..cb+NJ-1.
// Xw[j] holds x(s-12) (read, then overwritten with fresh x(s+24));
// Xm[j] holds x(s); Xn[j] holds x(s+12).
// Tw[j] <- sq_tot(s); Tr[j] gives sq_tot(s-24).
// Lb[j]: read winsum(s-12), write winsum(s)  (12-delay).
template<bool EDGE, bool LOAD, int NJ>
__device__ __forceinline__ void chunkN(
    const float* __restrict__ base, float* __restrict__ obase,
    float2 (&Xw)[12], float2 (&Xm)[12], float2 (&Xn)[12],
    float (&Tw)[12], float (&Tr)[12], float2 (&Lb)[12],
    float2& lead, float& varsum, int cb, int t0)
{
#pragma unroll
    for (int j = 0; j < NJ; ++j) {
        const int s = cb + j;
        const float2 xold = Xw[j];                 // x(s-12)
        if (LOAD) Xw[j] = ldg<EDGE>(base, s + 24); // consumed 12 iters later
        const float2 xmid = Xn[j];                 // x(s+12)
        lead.x += xmid.x - xold.x;                 // lead -> winsum(s)
        lead.y += xmid.y - xold.y;
        const float2 xcur = Xm[j];                 // x(s)
        float invc;
        if (EDGE) {
            const int cnt = min(s + 12, Sdim - 1) - max(s - 11, 0) + 1;
            invc = __builtin_amdgcn_rcpf((float)cnt);
        } else {
            invc = 1.f / 24.f;
        }
        const float dx = xcur.x - lead.x * invc;
        const float dy = xcur.y - lead.y * invc;
        float st = dx * dx + dy * dy;
        if (EDGE && (unsigned)s >= (unsigned)Sdim) st = 0.f;  // zero-pad sq
        st = wsum(st);                             // 128-ch sq_tot(s)
        varsum += st - Tr[j];                      // -> sum sq_tot[s-23..s]
        Tw[j] = st;
        const float2 wq = Lb[j];                   // winsum(q), q = s-12
        Lb[j] = lead;
        const int q = s - 12;
        if (q >= t0) {                             // q < t0+TT always here
            float invq;
            if (EDGE) {
                const int cq = min(q + 12, Sdim - 1) - max(q - 11, 0) + 1;
                invq = __builtin_amdgcn_rcpf((float)cq);
            } else {
                invq = 1.f / 24.f;
            }
            const float istd = __builtin_amdgcn_rcpf(
                sqrtf(fmaxf(varsum, 0.f) * (1.f / 23.f)) + EPSv);
            float2 o;
            o.x = (xold.x - wq.x * invq) * istd;
            o.y = (xold.y - wq.y * invq) * istd;
            *reinterpret_cast<float2*>(obase + (size_t)q * Cdim) = o;
        }
    }
}

template<bool EDGE>
__device__ __forceinline__ void run_tile(
    const float* __restrict__ base, float* __restrict__ obase, int t0)
{
    float2 X0[12], X1[12], X2[12], Lb[12];
    float  T0[12], T1[12], T2[12];
    float2 lead = make_float2(0.f, 0.f);
    float  varsum = 0.f;

    // Preload: X0 = x(t0-24+j), X1 = x(t0-12+j), X2 = x(t0+j);
    // lead = winsum(t0-13) = sum x[t0-24 .. t0-1] = sum(X0+X1).
#pragma unroll
    for (int j = 0; j < 12; ++j) {
        X0[j] = ldg<EDGE>(base, t0 - 24 + j);
        X1[j] = ldg<EDGE>(base, t0 - 12 + j);
        X2[j] = ldg<EDGE>(base, t0 + j);
        T0[j] = 0.f; T1[j] = 0.f; T2[j] = 0.f;
        Lb[j] = make_float2(0.f, 0.f);
        lead.x += X0[j].x + X1[j].x;
        lead.y += X0[j].y + X1[j].y;
    }

    // 7 full chunks + one 4-iter partial: s = t0-12 .. t0+75
    // (outputs q = t0 .. t0+63).
    int cb = t0 - 12;
    chunkN<EDGE, true , 12>(base, obase, X0, X1, X2, T0, T1, Lb, lead, varsum, cb, t0); cb += 12;
    chunkN<EDGE, true , 12>(base, obase, X1, X2, X0, T1, T2, Lb, lead, varsum, cb, t0); cb += 12;
    chunkN<EDGE, true , 12>(base, obase, X2, X0, X1, T2, T0, Lb, lead, varsum, cb, t0); cb += 12;
    chunkN<EDGE, true , 12>(base, obase, X0, X1, X2, T0, T1, Lb, lead, varsum, cb, t0); cb += 12;
    chunkN<EDGE, true , 12>(base, obase, X1, X2, X0, T1, T2, Lb, lead, varsum, cb, t0); cb += 12;
    chunkN<EDGE, true , 12>(base, obase, X2, X0, X1, T2, T0, Lb, lead, varsum, cb, t0); cb += 12;
    chunkN<EDGE, true , 12>(base, obase, X0, X1, X2, T0, T1, Lb, lead, varsum, cb, t0); cb += 12;
    chunkN<EDGE, false,  4>(base, obase, X1, X2, X0, T1, T2, Lb, lead, varsum, cb, t0);
}

__global__ __launch_bounds__(256, 4)
void mzs_kernel(const float* __restrict__ x, float* __restrict__ y) {
    const int tid  = threadIdx.x;
    const int lane = tid & 63;
    const int wid  = blockIdx.x * 4 + (tid >> 6);   // 4096 waves
    const int b    = wid >> 7;                      // 128 tiles per batch
    const int ti   = wid & 127;
    const int t0   = ti * TT;
    const float* base  = x + (size_t)b * Sdim * Cdim + lane * 2;
    float*       obase = y + (size_t)b * Sdim * Cdim + lane * 2;
    if (ti == 0 || ti == NTb - 1) run_tile<true >(base, obase, t0);
    else                          run_tile<false>(base, obase, t0);
}

extern "C" void kernel_launch(void* const* d_in, const int* in_sizes, int n_in,
                              void* d_out, int out_size, void* d_ws, size_t ws_size,
                              hipStream_t stream) {
    const float* x = (const float*)d_in[0];
    float* y = (float*)d_out;
    // 4096 wave-tiles (32 batches x 128 tiles), 4 waves per 256-thread block
    mzs_kernel<<<dim3(1024), dim3(256), 0, stream>>>(x, y);
}

// Round 4
// 76.374 us; speedup vs baseline: 1.4843x; 1.4843x over previous
//
#include <hip/hip_runtime.h>
#include <math.h>

// MovingZScoreNorm: x[32,8192,128] f32, W=24.
// mean: TF SAME avg-pool with valid-count; var: windowed sum of channel-summed
// sq / (W-1); out = (x-mean)/(sqrt(var)+eps).
//
// One wave per (batch, 64-row tile); lane owns 2 channels (float2).
// Single global load per iteration: x(s+24). Delayed rows live in a 36-row
// register delay line (3 rotating banks x 12, static indexing via unrolled
// chunks). Output mean = lead window-sum delayed 12 iters (register bank).
// sq_tot 24-delay in 3 rotating register banks. No LDS storage.
// TT=64 -> 4096 waves (16 waves/CU). launch_bounds(256,2): cap 256 VGPR --
// (256,4) made the allocator squeeze to 64 VGPR and spill the delay line
// (WRITE_SIZE 131->208 MB of scratch). 108 VGPR naturally gives 4 waves/SIMD.

constexpr int Sdim = 8192;
constexpr int Cdim = 128;
constexpr int TT   = 64;             // output rows per wave
constexpr int NTb  = Sdim / TT;      // 128 tiles per batch
constexpr float EPSv = 1e-7f;

__device__ __forceinline__ float wsum(float v) {
#pragma unroll
    for (int m = 1; m < 64; m <<= 1) v += __shfl_xor(v, m, 64);
    return v;
}

template<bool EDGE>
__device__ __forceinline__ float2 ldg(const float* __restrict__ base, int r) {
    if (EDGE && (unsigned)r >= (unsigned)Sdim) return make_float2(0.f, 0.f);
    return *reinterpret_cast<const float2*>(base + (size_t)r * Cdim);
}

// One chunk of NJ iterations s = cb..cb+NJ-1.
// Xw[j] holds x(s-12) (read, then overwritten with fresh x(s+24));
// Xm[j] holds x(s); Xn[j] holds x(s+12).
// Tw[j] <- sq_tot(s); Tr[j] gives sq_tot(s-24).
// Lb[j]: read winsum(s-12), write winsum(s)  (12-delay).
template<bool EDGE, bool LOAD, int NJ>
__device__ __forceinline__ void chunkN(
    const float* __restrict__ base, float* __restrict__ obase,
    float2 (&Xw)[12], float2 (&Xm)[12], float2 (&Xn)[12],
    float (&Tw)[12], float (&Tr)[12], float2 (&Lb)[12],
    float2& lead, float& varsum, int cb, int t0)
{
#pragma unroll
    for (int j = 0; j < NJ; ++j) {
        const int s = cb + j;
        const float2 xold = Xw[j];                 // x(s-12)
        if (LOAD) Xw[j] = ldg<EDGE>(base, s + 24); // consumed 12 iters later
        const float2 xmid = Xn[j];                 // x(s+12)
        lead.x += xmid.x - xold.x;                 // lead -> winsum(s)
        lead.y += xmid.y - xold.y;
        const float2 xcur = Xm[j];                 // x(s)
        float invc;
        if (EDGE) {
            const int cnt = min(s + 12, Sdim - 1) - max(s - 11, 0) + 1;
            invc = __builtin_amdgcn_rcpf((float)cnt);
        } else {
            invc = 1.f / 24.f;
        }
        const float dx = xcur.x - lead.x * invc;
        const float dy = xcur.y - lead.y * invc;
        float st = dx * dx + dy * dy;
        if (EDGE && (unsigned)s >= (unsigned)Sdim) st = 0.f;  // zero-pad sq
        st = wsum(st);                             // 128-ch sq_tot(s)
        varsum += st - Tr[j];                      // -> sum sq_tot[s-23..s]
        Tw[j] = st;
        const float2 wq = Lb[j];                   // winsum(q), q = s-12
        Lb[j] = lead;
        const int q = s - 12;
        if (q >= t0) {                             // q < t0+TT always here
            float invq;
            if (EDGE) {
                const int cq = min(q + 12, Sdim - 1) - max(q - 11, 0) + 1;
                invq = __builtin_amdgcn_rcpf((float)cq);
            } else {
                invq = 1.f / 24.f;
            }
            const float istd = __builtin_amdgcn_rcpf(
                sqrtf(fmaxf(varsum, 0.f) * (1.f / 23.f)) + EPSv);
            float2 o;
            o.x = (xold.x - wq.x * invq) * istd;
            o.y = (xold.y - wq.y * invq) * istd;
            *reinterpret_cast<float2*>(obase + (size_t)q * Cdim) = o;
        }
    }
}

template<bool EDGE>
__device__ __forceinline__ void run_tile(
    const float* __restrict__ base, float* __restrict__ obase, int t0)
{
    float2 X0[12], X1[12], X2[12], Lb[12];
    float  T0[12], T1[12], T2[12];
    float2 lead = make_float2(0.f, 0.f);
    float  varsum = 0.f;

    // Preload: X0 = x(t0-24+j), X1 = x(t0-12+j), X2 = x(t0+j);
    // lead = winsum(t0-13) = sum x[t0-24 .. t0-1] = sum(X0+X1).
#pragma unroll
    for (int j = 0; j < 12; ++j) {
        X0[j] = ldg<EDGE>(base, t0 - 24 + j);
        X1[j] = ldg<EDGE>(base, t0 - 12 + j);
        X2[j] = ldg<EDGE>(base, t0 + j);
        T0[j] = 0.f; T1[j] = 0.f; T2[j] = 0.f;
        Lb[j] = make_float2(0.f, 0.f);
        lead.x += X0[j].x + X1[j].x;
        lead.y += X0[j].y + X1[j].y;
    }

    // 7 full chunks + one 4-iter partial: s = t0-12 .. t0+75
    // (outputs q = t0 .. t0+63).
    int cb = t0 - 12;
    chunkN<EDGE, true , 12>(base, obase, X0, X1, X2, T0, T1, Lb, lead, varsum, cb, t0); cb += 12;
    chunkN<EDGE, true , 12>(base, obase, X1, X2, X0, T1, T2, Lb, lead, varsum, cb, t0); cb += 12;
    chunkN<EDGE, true , 12>(base, obase, X2, X0, X1, T2, T0, Lb, lead, varsum, cb, t0); cb += 12;
    chunkN<EDGE, true , 12>(base, obase, X0, X1, X2, T0, T1, Lb, lead, varsum, cb, t0); cb += 12;
    chunkN<EDGE, true , 12>(base, obase, X1, X2, X0, T1, T2, Lb, lead, varsum, cb, t0); cb += 12;
    chunkN<EDGE, true , 12>(base, obase, X2, X0, X1, T2, T0, Lb, lead, varsum, cb, t0); cb += 12;
    chunkN<EDGE, true , 12>(base, obase, X0, X1, X2, T0, T1, Lb, lead, varsum, cb, t0); cb += 12;
    chunkN<EDGE, false,  4>(base, obase, X1, X2, X0, T1, T2, Lb, lead, varsum, cb, t0);
}

__global__ __launch_bounds__(256, 2)
void mzs_kernel(const float* __restrict__ x, float* __restrict__ y) {
    const int tid  = threadIdx.x;
    const int lane = tid & 63;
    const int wid  = blockIdx.x * 4 + (tid >> 6);   // 4096 waves
    const int b    = wid >> 7;                      // 128 tiles per batch
    const int ti   = wid & 127;
    const int t0   = ti * TT;
    const float* base  = x + (size_t)b * Sdim * Cdim + lane * 2;
    float*       obase = y + (size_t)b * Sdim * Cdim + lane * 2;
    if (ti == 0 || ti == NTb - 1) run_tile<true >(base, obase, t0);
    else                          run_tile<false>(base, obase, t0);
}

extern "C" void kernel_launch(void* const* d_in, const int* in_sizes, int n_in,
                              void* d_out, int out_size, void* d_ws, size_t ws_size,
                              hipStream_t stream) {
    const float* x = (const float*)d_in[0];
    float* y = (float*)d_out;
    // 4096 wave-tiles (32 batches x 128 tiles), 4 waves per 256-thread block
    mzs_kernel<<<dim3(1024), dim3(256), 0, stream>>>(x, y);
}

// Round 7
// 61.410 us; speedup vs baseline: 1.8460x; 1.2437x over previous
//
#include <hip/hip_runtime.h>
#include <math.h>

// MovingZScoreNorm: x[32,8192,128] f32, W=24.
// mean: TF SAME avg-pool with valid-count; var: windowed sum of channel-summed
// sq / (W-1); out = (x-mean)/(sqrt(var)+eps).
//
// One wave per (batch, 128-row tile); lane owns 2 channels (float2).
// Single global load per iteration: x(s+24); 36-row register delay line
// (3 rotating banks x 12, static indexing). Output mean = lead window-sum
// delayed 12 iters (register bank).
//
// R5: NO per-row 64-lane reduce. st and the variance running-sum are kept
// PER-LANE (reduction commutes with the window sum); one batched cross-lane
// reduction per 4 output rows (4 independent butterfly chains, ILP-4) takes
// the shuffle latency off the per-row critical path.
// R7 fix: restore the UPPER output guard (q0 < t0+TT). R6 dropped it; the
// final chunk's batch q0 = t0+128 wrote 4 rows past the tile -> OOB page
// fault on the last tile of each batch.

constexpr int Sdim = 8192;
constexpr int Cdim = 128;
constexpr int TT   = 128;            // output rows per wave
constexpr int NTb  = Sdim / TT;      // 64 tiles per batch
constexpr float EPSv = 1e-7f;

typedef float floatx2 __attribute__((ext_vector_type(2)));

template<bool EDGE>
__device__ __forceinline__ float2 ldg(const float* __restrict__ base, int r) {
    if (EDGE && (unsigned)r >= (unsigned)Sdim) return make_float2(0.f, 0.f);
    return *reinterpret_cast<const float2*>(base + (size_t)r * Cdim);
}

__device__ __forceinline__ void ntst(float* p, float a, float b) {
    floatx2 v; v.x = a; v.y = b;
    __builtin_nontemporal_store(v, reinterpret_cast<floatx2*>(p));
}

// One chunk of 12 iterations s = cb..cb+11 (12 % 4 == 0: output batches of 4
// stay chunk-aligned).
// Xw[j]: x(s-12) (read, then overwritten with fresh x(s+24));
// Xm[j]: x(s); Xn[j]: x(s+12).
// Tw[j] <- st_lane(s); Tr[j] gives st_lane(s-24).
// Lb[j]: read winsum(s-12), write winsum(s)  (12-delay).
template<bool EDGE, bool LOAD>
__device__ __forceinline__ void chunk12(
    const float* __restrict__ base, float* __restrict__ obase,
    float2 (&Xw)[12], float2 (&Xm)[12], float2 (&Xn)[12],
    float (&Tw)[12], float (&Tr)[12], float2 (&Lb)[12],
    float2& lead, float& varsum, int cb, int t0)
{
    float2 onum[4];                  // per-row output numerators (batch of 4)
    float  vs4[4];                   // per-lane varsum snapshots
#pragma unroll
    for (int j = 0; j < 12; ++j) {
        const int s = cb + j;
        const float2 xold = Xw[j];                 // x(s-12)
        if (LOAD) Xw[j] = ldg<EDGE>(base, s + 24); // consumed 12 iters later
        const float2 xmid = Xn[j];                 // x(s+12)
        lead.x += xmid.x - xold.x;                 // lead -> winsum(s)
        lead.y += xmid.y - xold.y;
        const float2 xcur = Xm[j];                 // x(s)
        float invc;
        if (EDGE) {
            const int cnt = min(s + 12, Sdim - 1) - max(s - 11, 0) + 1;
            invc = __builtin_amdgcn_rcpf((float)cnt);
        } else {
            invc = 1.f / 24.f;
        }
        const float dx = xcur.x - lead.x * invc;
        const float dy = xcur.y - lead.y * invc;
        float st = dx * dx + dy * dy;              // PER-LANE (2 channels)
        if (EDGE && (unsigned)s >= (unsigned)Sdim) st = 0.f;  // zero-pad sq
        varsum += st - Tr[j];                      // per-lane window sum
        Tw[j] = st;
        const float2 wq = Lb[j];                   // winsum(q), q = s-12
        Lb[j] = lead;
        float invq;
        if (EDGE) {
            const int q = s - 12;
            const int cq = min(q + 12, Sdim - 1) - max(q - 11, 0) + 1;
            invq = __builtin_amdgcn_rcpf((float)cq);
        } else {
            invq = 1.f / 24.f;
        }
        onum[j & 3].x = xold.x - wq.x * invq;      // (x(q) - mean(q))
        onum[j & 3].y = xold.y - wq.y * invq;
        vs4[j & 3] = varsum;

        if ((j & 3) == 3) {                        // batch of 4 output rows
            const int q0 = s - 15;                 // q0..q0+3 (4-aligned vs t0)
            if (q0 >= t0 && q0 < t0 + TT) {        // both guards! (R7 fix)
                float r0 = vs4[0], r1 = vs4[1], r2 = vs4[2], r3 = vs4[3];
#pragma unroll
                for (int m = 1; m < 64; m <<= 1) { // 4 independent chains
                    r0 += __shfl_xor(r0, m, 64);
                    r1 += __shfl_xor(r1, m, 64);
                    r2 += __shfl_xor(r2, m, 64);
                    r3 += __shfl_xor(r3, m, 64);
                }
                const float i0 = __builtin_amdgcn_rcpf(
                    sqrtf(fmaxf(r0, 0.f) * (1.f / 23.f)) + EPSv);
                const float i1 = __builtin_amdgcn_rcpf(
                    sqrtf(fmaxf(r1, 0.f) * (1.f / 23.f)) + EPSv);
                const float i2 = __builtin_amdgcn_rcpf(
                    sqrtf(fmaxf(r2, 0.f) * (1.f / 23.f)) + EPSv);
                const float i3 = __builtin_amdgcn_rcpf(
                    sqrtf(fmaxf(r3, 0.f) * (1.f / 23.f)) + EPSv);
                ntst(obase + (size_t)(q0    ) * Cdim, onum[0].x * i0, onum[0].y * i0);
                ntst(obase + (size_t)(q0 + 1) * Cdim, onum[1].x * i1, onum[1].y * i1);
                ntst(obase + (size_t)(q0 + 2) * Cdim, onum[2].x * i2, onum[2].y * i2);
                ntst(obase + (size_t)(q0 + 3) * Cdim, onum[3].x * i3, onum[3].y * i3);
            }
        }
    }
}

template<bool EDGE>
__device__ __forceinline__ void run_tile(
    const float* __restrict__ base, float* __restrict__ obase, int t0)
{
    float2 X0[12], X1[12], X2[12], Lb[12];
    float  T0[12], T1[12], T2[12];
    float2 lead = make_float2(0.f, 0.f);
    float  varsum = 0.f;

    // Preload: X0 = x(t0-24+j), X1 = x(t0-12+j), X2 = x(t0+j);
    // lead = winsum(t0-13) = sum x[t0-24 .. t0-1] = sum(X0+X1).
#pragma unroll
    for (int j = 0; j < 12; ++j) {
        X0[j] = ldg<EDGE>(base, t0 - 24 + j);
        X1[j] = ldg<EDGE>(base, t0 - 12 + j);
        X2[j] = ldg<EDGE>(base, t0 + j);
        T0[j] = 0.f; T1[j] = 0.f; T2[j] = 0.f;
        Lb[j] = make_float2(0.f, 0.f);
        lead.x += X0[j].x + X1[j].x;
        lead.y += X0[j].y + X1[j].y;
    }

    // 13 chunks of 12: s = t0-12 .. t0+143 (outputs q = t0 .. t0+127).
    int cb = t0 - 12;
    for (int k = 0; k < 4; ++k) {   // 3-chunk rotation, statically indexed
        chunk12<EDGE, true>(base, obase, X0, X1, X2, T0, T1, Lb, lead, varsum, cb, t0); cb += 12;
        chunk12<EDGE, true>(base, obase, X1, X2, X0, T1, T2, Lb, lead, varsum, cb, t0); cb += 12;
        chunk12<EDGE, true>(base, obase, X2, X0, X1, T2, T0, Lb, lead, varsum, cb, t0); cb += 12;
    }
    chunk12<EDGE, false>(base, obase, X0, X1, X2, T0, T1, Lb, lead, varsum, cb, t0);
}

__global__ __launch_bounds__(256, 2)
void mzs_kernel(const float* __restrict__ x, float* __restrict__ y) {
    const int tid  = threadIdx.x;
    const int lane = tid & 63;
    const int wid  = blockIdx.x * 4 + (tid >> 6);   // 2048 waves
    const int b    = wid >> 6;                      // 64 tiles per batch
    const int ti   = wid & 63;
    const int t0   = ti * TT;
    const float* base  = x + (size_t)b * Sdim * Cdim + lane * 2;
    float*       obase = y + (size_t)b * Sdim * Cdim + lane * 2;
    if (ti == 0 || ti == NTb - 1) run_tile<true >(base, obase, t0);
    else                          run_tile<false>(base, obase, t0);
}

extern "C" void kernel_launch(void* const* d_in, const int* in_sizes, int n_in,
                              void* d_out, int out_size, void* d_ws, size_t ws_size,
                              hipStream_t stream) {
    const float* x = (const float*)d_in[0];
    float* y = (float*)d_out;
    // 2048 wave-tiles (32 batches x 64 tiles), 4 waves per 256-thread block
    mzs_kernel<<<dim3(512), dim3(256), 0, stream>>>(x, y);
}

// Round 11
// 55.738 us; speedup vs baseline: 2.0338x; 1.1018x over previous
//
#include <hip/hip_runtime.h>
#include <math.h>

// MovingZScoreNorm: x[32,8192,128] f32, W=24.
// mean: TF SAME avg-pool with valid-count; var: windowed sum of channel-summed
// sq / (W-1); out = (x-mean)/(sqrt(var)+eps).
//
// One wave per (batch, 128-row tile); lane owns 2 channels (float2).
// Single global load per iteration: x(s+24); 36-row register delay line
// (3 rotating banks x 12, static indexing). Output mean = lead window-sum
// delayed 12 iters (register bank). Per-lane variance running-sum; batched
// cross-lane reduction per 4 output rows.
//
// R8: all-VALU 64-lane allreduce (permlane swaps + DPP row_ror tree).
// R10: hand-rolled swap asm replaced by the compiler-modeled builtins
// __builtin_amdgcn_permlane{32,16}_swap (returns {vdst,vsrc} as SSA values;
// no asm register-aliasing traps). r.x + r.y = exact pairwise sum at
// distance 32/16 in every lane.

constexpr int Sdim = 8192;
constexpr int Cdim = 128;
constexpr int TT   = 128;            // output rows per wave
constexpr int NTb  = Sdim / TT;      // 64 tiles per batch
constexpr float EPSv = 1e-7f;

typedef float floatx2 __attribute__((ext_vector_type(2)));
typedef unsigned int uintx2 __attribute__((ext_vector_type(2)));

template<bool EDGE>
__device__ __forceinline__ float2 ldg(const float* __restrict__ base, int r) {
    if (EDGE && (unsigned)r >= (unsigned)Sdim) return make_float2(0.f, 0.f);
    return *reinterpret_cast<const float2*>(base + (size_t)r * Cdim);
}

__device__ __forceinline__ void ntst(float* p, float a, float b) {
    floatx2 v; v.x = a; v.y = b;
    __builtin_nontemporal_store(v, reinterpret_cast<floatx2*>(p));
}

template<int N>
__device__ __forceinline__ float dpp_ror_add(float v) {
    // v + row_ror:N(v)   (rotation within each 16-lane row; VALU pipe)
    int r = __builtin_amdgcn_update_dpp(0, __float_as_int(v),
                                        0x120 | N, 0xf, 0xf, true);
    return v + __int_as_float(r);
}

__device__ __forceinline__ float swap32_add(float v) {
    // {vdst,vsrc} = permlane32_swap(v, v): vdst = {lo(v), lo(v)},
    // vsrc = {hi(v), hi(v)} -> sum = v[l] + v[l^32] in every lane.
    const unsigned u = __float_as_uint(v);
    uintx2 r = __builtin_amdgcn_permlane32_swap(u, u, false, false);
    return __uint_as_float(r.x) + __uint_as_float(r.y);
}

__device__ __forceinline__ float swap16_add(float v) {
    // odd rows of vdst <-> even rows of vsrc: sum = v[l] + v[l^16].
    const unsigned u = __float_as_uint(v);
    uintx2 r = __builtin_amdgcn_permlane16_swap(u, u, false, false);
    return __uint_as_float(r.x) + __uint_as_float(r.y);
}

__device__ __forceinline__ float wave_allsum(float v) {
    v = swap32_add(v);       // v[l] + v[l^32]
    v = swap16_add(v);       // + distance 16
    v = dpp_ror_add<8>(v);   // row rotations: all 16 lanes of each row
    v = dpp_ror_add<4>(v);
    v = dpp_ror_add<2>(v);
    v = dpp_ror_add<1>(v);
    return v;                // total of 64 lanes, in every lane
}

// One chunk of 12 iterations s = cb..cb+11 (12 % 4 == 0: output batches of 4
// stay chunk-aligned).
// Xw[j]: x(s-12) (read, then overwritten with fresh x(s+24));
// Xm[j]: x(s); Xn[j]: x(s+12).
// Tw[j] <- st_lane(s); Tr[j] gives st_lane(s-24).
// Lb[j]: read winsum(s-12), write winsum(s)  (12-delay).
template<bool EDGE, bool LOAD>
__device__ __forceinline__ void chunk12(
    const float* __restrict__ base, float* __restrict__ obase,
    float2 (&Xw)[12], float2 (&Xm)[12], float2 (&Xn)[12],
    float (&Tw)[12], float (&Tr)[12], float2 (&Lb)[12],
    float2& lead, float& varsum, int cb, int t0)
{
    float2 onum[4];                  // per-row output numerators (batch of 4)
    float  vs4[4];                   // per-lane varsum snapshots
#pragma unroll
    for (int j = 0; j < 12; ++j) {
        const int s = cb + j;
        const float2 xold = Xw[j];                 // x(s-12)
        if (LOAD) Xw[j] = ldg<EDGE>(base, s + 24); // consumed 12 iters later
        const float2 xmid = Xn[j];                 // x(s+12)
        lead.x += xmid.x - xold.x;                 // lead -> winsum(s)
        lead.y += xmid.y - xold.y;
        const float2 xcur = Xm[j];                 // x(s)
        float invc;
        if (EDGE) {
            const int cnt = min(s + 12, Sdim - 1) - max(s - 11, 0) + 1;
            invc = __builtin_amdgcn_rcpf((float)cnt);
        } else {
            invc = 1.f / 24.f;
        }
        const float dx = xcur.x - lead.x * invc;
        const float dy = xcur.y - lead.y * invc;
        float st = dx * dx + dy * dy;              // PER-LANE (2 channels)
        if (EDGE && (unsigned)s >= (unsigned)Sdim) st = 0.f;  // zero-pad sq
        varsum += st - Tr[j];                      // per-lane window sum
        Tw[j] = st;
        const float2 wq = Lb[j];                   // winsum(q), q = s-12
        Lb[j] = lead;
        float invq;
        if (EDGE) {
            const int q = s - 12;
            const int cq = min(q + 12, Sdim - 1) - max(q - 11, 0) + 1;
            invq = __builtin_amdgcn_rcpf((float)cq);
        } else {
            invq = 1.f / 24.f;
        }
        onum[j & 3].x = xold.x - wq.x * invq;      // (x(q) - mean(q))
        onum[j & 3].y = xold.y - wq.y * invq;
        vs4[j & 3] = varsum;

        if ((j & 3) == 3) {                        // batch of 4 output rows
            const int q0 = s - 15;                 // q0..q0+3 (4-aligned vs t0)
            if (q0 >= t0 && q0 < t0 + TT) {
                // 4 independent all-VALU reduces (compiler interleaves)
                const float r0 = wave_allsum(vs4[0]);
                const float r1 = wave_allsum(vs4[1]);
                const float r2 = wave_allsum(vs4[2]);
                const float r3 = wave_allsum(vs4[3]);
                const float i0 = __builtin_amdgcn_rcpf(
                    __builtin_amdgcn_sqrtf(fmaxf(r0, 0.f) * (1.f / 23.f)) + EPSv);
                const float i1 = __builtin_amdgcn_rcpf(
                    __builtin_amdgcn_sqrtf(fmaxf(r1, 0.f) * (1.f / 23.f)) + EPSv);
                const float i2 = __builtin_amdgcn_rcpf(
                    __builtin_amdgcn_sqrtf(fmaxf(r2, 0.f) * (1.f / 23.f)) + EPSv);
                const float i3 = __builtin_amdgcn_rcpf(
                    __builtin_amdgcn_sqrtf(fmaxf(r3, 0.f) * (1.f / 23.f)) + EPSv);
                ntst(obase + (size_t)(q0    ) * Cdim, onum[0].x * i0, onum[0].y * i0);
                ntst(obase + (size_t)(q0 + 1) * Cdim, onum[1].x * i1, onum[1].y * i1);
                ntst(obase + (size_t)(q0 + 2) * Cdim, onum[2].x * i2, onum[2].y * i2);
                ntst(obase + (size_t)(q0 + 3) * Cdim, onum[3].x * i3, onum[3].y * i3);
            }
        }
    }
}

template<bool EDGE>
__device__ __forceinline__ void run_tile(
    const float* __restrict__ base, float* __restrict__ obase, int t0)
{
    float2 X0[12], X1[12], X2[12], Lb[12];
    float  T0[12], T1[12], T2[12];
    float2 lead = make_float2(0.f, 0.f);
    float  varsum = 0.f;

    // Preload: X0 = x(t0-24+j), X1 = x(t0-12+j), X2 = x(t0+j);
    // lead = winsum(t0-13) = sum x[t0-24 .. t0-1] = sum(X0+X1).
#pragma unroll
    for (int j = 0; j < 12; ++j) {
        X0[j] = ldg<EDGE>(base, t0 - 24 + j);
        X1[j] = ldg<EDGE>(base, t0 - 12 + j);
        X2[j] = ldg<EDGE>(base, t0 + j);
        T0[j] = 0.f; T1[j] = 0.f; T2[j] = 0.f;
        Lb[j] = make_float2(0.f, 0.f);
        lead.x += X0[j].x + X1[j].x;
        lead.y += X0[j].y + X1[j].y;
    }

    // 13 chunks of 12: s = t0-12 .. t0+143 (outputs q = t0 .. t0+127).
    int cb = t0 - 12;
    for (int k = 0; k < 4; ++k) {   // 3-chunk rotation, statically indexed
        chunk12<EDGE, true>(base, obase, X0, X1, X2, T0, T1, Lb, lead, varsum, cb, t0); cb += 12;
        chunk12<EDGE, true>(base, obase, X1, X2, X0, T1, T2, Lb, lead, varsum, cb, t0); cb += 12;
        chunk12<EDGE, true>(base, obase, X2, X0, X1, T2, T0, Lb, lead, varsum, cb, t0); cb += 12;
    }
    chunk12<EDGE, false>(base, obase, X0, X1, X2, T0, T1, Lb, lead, varsum, cb, t0);
}

__global__ __launch_bounds__(256, 2)
void mzs_kernel(const float* __restrict__ x, float* __restrict__ y) {
    const int tid  = threadIdx.x;
    const int lane = tid & 63;
    const int wid  = blockIdx.x * 4 + (tid >> 6);   // 2048 waves
    const int b    = wid >> 6;                      // 64 tiles per batch
    const int ti   = wid & 63;
    const int t0   = ti * TT;
    const float* base  = x + (size_t)b * Sdim * Cdim + lane * 2;
    float*       obase = y + (size_t)b * Sdim * Cdim + lane * 2;
    if (ti == 0 || ti == NTb - 1) run_tile<true >(base, obase, t0);
    else                          run_tile<false>(base, obase, t0);
}

extern "C" void kernel_launch(void* const* d_in, const int* in_sizes, int n_in,
                              void* d_out, int out_size, void* d_ws, size_t ws_size,
                              hipStream_t stream) {
    const float* x = (const float*)d_in[0];
    float* y = (float*)d_out;
    // 2048 wave-tiles (32 batches x 64 tiles), 4 waves per 256-thread block
    mzs_kernel<<<dim3(512), dim3(256), 0, stream>>>(x, y);
}